// Round 1
// 94.782 us; speedup vs baseline: 1.0676x; 1.0676x over previous
//
#include <hip/hip_runtime.h>
#include <math.h>

#define NS 8192          // sampled points per part (24576/3)
#define NPTS 24576
#define YSPLIT 16
#define YTILE 512        // NS / YSPLIT
#define BX 256
#define XPT 4
#define XB (NS / (BX * XPT))   // 8

// ws float layout:
// [0..3]    accum per combo (combo = part*2 + dir)
// [36]      e_kin
// [40]      ticket counter (int)
// [131136..] partial mins: [4 combos][YSPLIT][NS]
#define PARTIAL_OFF 131136

__device__ __forceinline__ void make_T12(const float* __restrict__ rq,
                                         const float* __restrict__ tra,
                                         int p, float* T) {
    float a = rq[p * 4 + 0], b = rq[p * 4 + 1];
    float c = rq[p * 4 + 2], d = rq[p * 4 + 3];
    float inv = rsqrtf(a * a + b * b + c * c + d * d);
    a *= inv; b *= inv; c *= inv; d *= inv;
    T[0]  = 1.f - 2.f * c * c - 2.f * d * d;
    T[1]  = 2.f * b * c - 2.f * a * d;
    T[2]  = 2.f * a * c + 2.f * b * d;
    T[3]  = tra[p * 3 + 0];
    T[4]  = 2.f * b * c + 2.f * a * d;
    T[5]  = 1.f - 2.f * b * b - 2.f * d * d;
    T[6]  = 2.f * c * d - 2.f * a * b;
    T[7]  = tra[p * 3 + 1];
    T[8]  = 2.f * b * d - 2.f * a * c;
    T[9]  = 2.f * a * b + 2.f * c * d;
    T[10] = 1.f - 2.f * b * b - 2.f * c * c;
    T[11] = tra[p * 3 + 2];
}

// Fused: transform-on-the-fly + chamfer partial mins. Also does the tiny
// "prep" duties (transforms->out, e_kin, accum/ticket zeroing) on one thread.
__global__ __launch_bounds__(BX) void chamfer_fused(
    const float* __restrict__ cam, const float* __restrict__ cad,
    const float* __restrict__ rq,  const float* __restrict__ tr,
    const float* __restrict__ ja,
    float* __restrict__ ws, float* __restrict__ out)
{
    int combo = blockIdx.y;
    int p   = combo >> 1;
    int dir = combo & 1;

    float T[12];
    make_T12(rq, tr, p, T);

    // housekeeping: one thread in the whole grid
    if (blockIdx.x == 0 && blockIdx.y == 0 && blockIdx.z == 0 && threadIdx.x == 0) {
        float TT[2][16];
        for (int q = 0; q < 2; ++q) {
            make_T12(rq, tr, q, TT[q]);
            TT[q][12] = 0.f; TT[q][13] = 0.f; TT[q][14] = 0.f; TT[q][15] = 1.f;
            for (int k = 0; k < 16; ++k) out[2 + q * 16 + k] = TT[q][k];
        }
        float ss = 0.f;
        for (int i = 0; i < 4; ++i) {
            for (int j = 0; j < 2; ++j) {
                float d0 = 0.f, d1 = 0.f;
                for (int k = 0; k < 4; ++k) {
                    d0 += TT[0][i * 4 + k] * ja[0 * 8 + j * 4 + k];
                    d1 += TT[1][i * 4 + k] * ja[1 * 8 + j * 4 + k];
                }
                float df = d0 - d1;
                ss += df * df;
            }
        }
        float ek = 1.f / (1.f + expf(5.f * sqrtf(ss)));
        ws[36] = ek;
        out[1] = ek;
        ws[0] = 0.f; ws[1] = 0.f; ws[2] = 0.f; ws[3] = 0.f;
        *(int*)(ws + 40) = 0;
    }

    // ---- X setup: load raw points, transform if cad side ----
    int xbase = blockIdx.x * (BX * XPT) + threadIdx.x;
    const float* xsrc = (dir == 0 ? cad : cam) + p * NPTS * 3;
    float m0[XPT], m1[XPT], m2[XPT], s[XPT], dmin[XPT];
#pragma unroll
    for (int k = 0; k < XPT; ++k) {
        int i = xbase + k * BX;
        const float* sp = xsrc + i * 9;   // sample step 3 -> 9 floats
        float x = sp[0], y = sp[1], z = sp[2];
        if (dir == 0) {
            float tx = T[0] * x + T[1] * y + T[2]  * z + T[3];
            float ty = T[4] * x + T[5] * y + T[6]  * z + T[7];
            float tz = T[8] * x + T[9] * y + T[10] * z + T[11];
            x = tx; y = ty; z = tz;
        }
        m0[k] = -2.f * x; m1[k] = -2.f * y; m2[k] = -2.f * z;
        s[k]  = x * x + y * y + z * z;
        dmin[k] = 3.4e38f;
    }

    // ---- Y staging into LDS (transform if cad side) ----
    __shared__ float4 sy[YTILE];
    const float* ysrc = (dir == 0 ? cam : cad) + p * NPTS * 3;
    int ybase = blockIdx.z * YTILE;
#pragma unroll
    for (int t = 0; t < YTILE / BX; ++t) {
        int i = ybase + t * BX + threadIdx.x;
        const float* sp = ysrc + i * 9;
        float x = sp[0], y = sp[1], z = sp[2];
        if (dir == 1) {
            float tx = T[0] * x + T[1] * y + T[2]  * z + T[3];
            float ty = T[4] * x + T[5] * y + T[6]  * z + T[7];
            float tz = T[8] * x + T[9] * y + T[10] * z + T[11];
            x = tx; y = ty; z = tz;
        }
        sy[t * BX + threadIdx.x] = make_float4(x, y, z, x * x + y * y + z * z);
    }
    __syncthreads();

    // ---- inner loop: 3 FMA/pair + min3 per y-pair (s hoisted out) ----
#pragma unroll 4
    for (int j = 0; j < YTILE; j += 2) {
        float4 ya = sy[j];
        float4 yb = sy[j + 1];
#pragma unroll
        for (int k = 0; k < XPT; ++k) {
            float da = fmaf(m0[k], ya.x, ya.w);
            da = fmaf(m1[k], ya.y, da);
            da = fmaf(m2[k], ya.z, da);
            float db = fmaf(m0[k], yb.x, yb.w);
            db = fmaf(m1[k], yb.y, db);
            db = fmaf(m2[k], yb.z, db);
            dmin[k] = fminf(dmin[k], fminf(da, db));   // -> v_min3_f32
        }
    }

    float* partial = ws + PARTIAL_OFF + combo * (YSPLIT * NS) + blockIdx.z * NS;
#pragma unroll
    for (int k = 0; k < XPT; ++k) {
        partial[xbase + k * BX] = s[k] + dmin[k];
    }
}

// Fused reduce + finalize: last block (atomic ticket) writes out[0].
__global__ __launch_bounds__(256) void reduce_final(
    float* __restrict__ ws, const float* __restrict__ pw,
    float* __restrict__ out)
{
    int combo = blockIdx.y;
    int x = blockIdx.x * 256 + threadIdx.x;
    const float* p = ws + PARTIAL_OFF + combo * (YSPLIT * NS) + x;
    float m = p[0];
#pragma unroll
    for (int ysi = 1; ysi < YSPLIT; ++ysi) m = fminf(m, p[ysi * NS]);
    float d = sqrtf(fmaxf(m, 0.f));
#pragma unroll
    for (int off = 32; off > 0; off >>= 1) d += __shfl_down(d, off, 64);

    __shared__ float sm[4];
    __shared__ bool last;
    int wid = threadIdx.x >> 6;
    if ((threadIdx.x & 63) == 0) sm[wid] = d;
    __syncthreads();
    if (threadIdx.x == 0) {
        float sum = sm[0] + sm[1] + sm[2] + sm[3];
        atomicAdd(&ws[combo], sum);
        __threadfence();
        int t = atomicAdd((int*)(ws + 40), 1);
        last = (t == 4 * (NS / 256) - 1);   // 127
    }
    __syncthreads();
    if (last && threadIdx.x == 0) {
        // atomic reads bypass any stale cache path (cross-XCD safe)
        float a0 = atomicAdd(&ws[0], 0.f);
        float a1 = atomicAdd(&ws[1], 0.f);
        float a2 = atomicAdd(&ws[2], 0.f);
        float a3 = atomicAdd(&ws[3], 0.f);
        float e0 = (a0 + a1) * (1.f / NS);
        float e1 = (a2 + a3) * (1.f / NS);
        out[0] = pw[0] * e0 + pw[1] * e1 + pw[2] * ws[36];
    }
}

extern "C" void kernel_launch(void* const* d_in, const int* in_sizes, int n_in,
                              void* d_out, int out_size, void* d_ws, size_t ws_size,
                              hipStream_t stream) {
    const float* cam = (const float*)d_in[0];
    const float* cad = (const float*)d_in[1];
    const float* pw  = (const float*)d_in[2];
    const float* rq  = (const float*)d_in[3];
    const float* tr  = (const float*)d_in[4];
    const float* ja  = (const float*)d_in[5];
    float* out = (float*)d_out;
    float* ws  = (float*)d_ws;

    dim3 cg(XB, 4, YSPLIT);
    chamfer_fused<<<cg, BX, 0, stream>>>(cam, cad, rq, tr, ja, ws, out);
    reduce_final<<<dim3(NS / 256, 4), 256, 0, stream>>>(ws, pw, out);
}